// Round 6
// baseline (2240.636 us; speedup 1.0000x reference)
//
#include <hip/hip_runtime.h>

// LocallyConnected2D: y[n,h,w] = relu(sum_{i,j} x[n,h+i,w+j]*W[h,w,i,j] + b[h,w])
// lane = batch n (N=64=wave). History:
//  R1: weights scalarized (s_load) -> lgkmcnt drains. WRITE=65MB (clean, no spill).
//  R2: f[12] local array -> scratch (WRITE 223MB).
//  R3: uniform VMEM weights, no pipeline -> hoist pressure, spill (191MB).
//  R4: weights via LDS (best, 271us) but compiler hoisted the unrolled ds_reads,
//      hit 128-VGPR cap, spilled (WRITE 190.6MB).
//  R5: manual cur/nxt prefetch + asm memory clobber -> arrays forced to scratch,
//      flushed per iteration (WRITE 1.78GB). Never again.
//  R6: R4 structure + (1) ALL staging via global_load_lds (no VGPRs in staging),
//      (2) sched_barrier(0x7) per k-half to bound ds_read hoisting -> live set
//      ~90 VGPRs, no spill by construction.

#define H_IN 512
#define W_IN 512
#define H_OUT 504
#define W_OUT 504
#define W_T 8
#define H_T 4
#define TROWS (H_T + 8)        // 12 staged input rows
#define XF (TROWS * 1024)      // 12288 floats = 48 KB x tile
#define WFLO 648               // weight floats per output-row chunk (8*81)
#define WLDS (H_T * WFLO)      // 2592 floats = 10.125 KB

typedef const __attribute__((address_space(1))) void* gas_t;
typedef __attribute__((address_space(3))) void* las_t;

// async global->LDS, 16B per lane; LDS dest = uniform base + lane*16 (HW rule)
__device__ __forceinline__ void gl_lds16(const float* g, float* l) {
    __builtin_amdgcn_global_load_lds((gas_t)g, (las_t)l, 16, 0, 0);
}

__launch_bounds__(256, 2)
__global__ void lc2d_kernel(const float* __restrict__ x,
                            const float* __restrict__ weight,
                            const float* __restrict__ bias,
                            float* __restrict__ out) {
    // LDS: x tile [row 0..11][cgrp 0..3][n 0..63][4] = 48 KB, then weights
    //      [row 0..3][648 floats] = 10.125 KB. Total 58.125 KB -> 2 blocks/CU.
    __shared__ float lds[XF + WLDS];

    const int t    = threadIdx.x;
    const int lane = t & 63;          // batch index n
    const int wv   = t >> 6;          // wave 0..3

    const int h0 = blockIdx.y * H_T;
    const int w0 = blockIdx.x * W_T;

    // ---- stage x tile: wave wv stages cgrp=wv plane, rows 0..11 ----
    // per-lane global addr (scattered, n-stride 1MB), LDS dest uniform+lane*16.
    {
        const float* gx = x + (size_t)lane * (H_IN * W_IN)
                            + (size_t)h0 * W_IN + w0 + wv * 4;
        #pragma unroll
        for (int row = 0; row < TROWS; ++row)
            gl_lds16(gx + row * W_IN, &lds[row * 1024 + wv * 256]);
    }

    // ---- stage weights: wave wv stages row chunk wv (648 floats, coalesced) ----
    {
        const float* gw = weight + ((size_t)(h0 + wv) * W_OUT + w0) * 81;
        float* lw = &lds[XF + wv * WFLO];
        gl_lds16(gw + lane * 4,       lw);         // floats   0..255
        gl_lds16(gw + 256 + lane * 4, lw + 256);   // floats 256..511
        if (lane < 34)
            gl_lds16(gw + 512 + lane * 4, lw + 512); // floats 512..647
    }
    __syncthreads();   // drains vmcnt (global_load_lds) for the whole block

    const int wvu = __builtin_amdgcn_readfirstlane(wv);
    const int h   = h0 + wvu;                      // this wave's output row

    float acc[W_T];
    {
        const float* bptr = bias + (size_t)h * W_OUT + w0;
        #pragma unroll
        for (int k = 0; k < W_T; ++k) acc[k] = bptr[k];
    }

    // wave-uniform weight base in LDS -> broadcast ds_read_b128, imm offsets
    const float* wlds = &lds[XF + wvu * WFLO];

    #pragma unroll
    for (int r = 0; r < 9; ++r) {
        // x row (wv + r): 16 floats/lane via 4 conflict-free ds_read_b128
        float xr[16];
        const int lrow = wv + r;
        #pragma unroll
        for (int c = 0; c < 4; ++c) {
            const float4 v = *reinterpret_cast<const float4*>(
                &lds[lrow * 1024 + c * 256 + lane * 4]);
            xr[4 * c + 0] = v.x; xr[4 * c + 1] = v.y;
            xr[4 * c + 2] = v.z; xr[4 * c + 3] = v.w;
        }

        #pragma unroll
        for (int kh = 0; kh < 2; ++kh) {           // k-halves: 0..3, 4..7
            #pragma unroll
            for (int kk = 0; kk < 4; ++kk) {
                const int k      = kh * 4 + kk;
                const int base   = k * 81 + r * 9; // compile-time after unroll
                const int astart = base & ~3;
                const int d      = base & 3;
                const float4 v0 = *reinterpret_cast<const float4*>(wlds + astart);
                const float4 v1 = *reinterpret_cast<const float4*>(wlds + astart + 4);
                const float4 v2 = *reinterpret_cast<const float4*>(wlds + astart + 8);
                float t0, t1, t2, t3, t4, t5, t6, t7, t8;
                if (d == 0) {
                    t0=v0.x; t1=v0.y; t2=v0.z; t3=v0.w; t4=v1.x; t5=v1.y; t6=v1.z; t7=v1.w; t8=v2.x;
                } else if (d == 1) {
                    t0=v0.y; t1=v0.z; t2=v0.w; t3=v1.x; t4=v1.y; t5=v1.z; t6=v1.w; t7=v2.x; t8=v2.y;
                } else if (d == 2) {
                    t0=v0.z; t1=v0.w; t2=v1.x; t3=v1.y; t4=v1.z; t5=v1.w; t6=v2.x; t7=v2.y; t8=v2.z;
                } else {
                    t0=v0.w; t1=v1.x; t2=v1.y; t3=v1.z; t4=v1.w; t5=v2.x; t6=v2.y; t7=v2.z; t8=v2.w;
                }
                acc[k] = fmaf(t0, xr[k + 0], acc[k]);
                acc[k] = fmaf(t1, xr[k + 1], acc[k]);
                acc[k] = fmaf(t2, xr[k + 2], acc[k]);
                acc[k] = fmaf(t3, xr[k + 3], acc[k]);
                acc[k] = fmaf(t4, xr[k + 4], acc[k]);
                acc[k] = fmaf(t5, xr[k + 5], acc[k]);
                acc[k] = fmaf(t6, xr[k + 6], acc[k]);
                acc[k] = fmaf(t7, xr[k + 7], acc[k]);
                acc[k] = fmaf(t8, xr[k + 8], acc[k]);
            }
            // Scheduling-only fence: ALU may cross, DS/VMEM may not.
            // Bounds ds_read hoisting -> live set stays ~90 VGPRs, no spill.
            __builtin_amdgcn_sched_barrier(0x7);
        }
    }

    // ---- epilogue: ReLU + store (1 row x 8 floats per lane, 16B-aligned) ----
    float* o = out + (size_t)lane * (H_OUT * W_OUT) + (size_t)h * W_OUT + w0;
    float4 s;
    s.x = fmaxf(acc[0], 0.f); s.y = fmaxf(acc[1], 0.f);
    s.z = fmaxf(acc[2], 0.f); s.w = fmaxf(acc[3], 0.f);
    *reinterpret_cast<float4*>(o) = s;
    s.x = fmaxf(acc[4], 0.f); s.y = fmaxf(acc[5], 0.f);
    s.z = fmaxf(acc[6], 0.f); s.w = fmaxf(acc[7], 0.f);
    *reinterpret_cast<float4*>(o + 4) = s;
}

extern "C" void kernel_launch(void* const* d_in, const int* in_sizes, int n_in,
                              void* d_out, int out_size, void* d_ws, size_t ws_size,
                              hipStream_t stream) {
    const float* x      = (const float*)d_in[0];
    const float* weight = (const float*)d_in[1];
    const float* bias   = (const float*)d_in[2];
    float* out          = (float*)d_out;

    dim3 grid(W_OUT / W_T, H_OUT / H_T);   // 63 x 126
    dim3 block(256);
    lc2d_kernel<<<grid, block, 0, stream>>>(x, weight, bias, out);
}

// Round 7
// 386.433 us; speedup vs baseline: 5.7983x; 5.7983x over previous
//
#include <hip/hip_runtime.h>

// LocallyConnected2D: y[n,h,w] = relu(sum_{i,j} x[n,h+i,w+j]*W[h,w,i,j] + b[h,w])
// lane = batch n (N=64=wave). History:
//  R1: scalar (SMEM) weights -> lgkmcnt drains mixed with ds_read. Clean regs.
//  R2: f[12] local array -> scratch (223MB writes).
//  R3: VMEM uniform weights + full unroll -> hoist pressure -> spill (191MB).
//  R4: weights via LDS broadcast -> hoisted ds_reads, 128-VGPR pin, spill (191MB).
//  R5: manual cur/nxt prefetch + memory clobber -> arrays in scratch (1.78GB).
//  R6: sched_barrier(0x7) regions -> allocator catastrophe (3.68GB scratch).
//  Lesson: the fully-unrolled select-ladder body triggers spill no matter the
//  fence. R7 = boring shape: RUNTIME r loop (unroll 1) bounds the scheduler
//  region to one iteration; 9 taps read directly as dwordx4+dwordx4+dword
//  (4B-aligned vector type, no select ladder); weights on vmcnt, x on lgkmcnt.

#define H_IN 512
#define W_IN 512
#define H_OUT 504
#define W_OUT 504
#define W_T 8
#define H_T 4
#define TROWS (H_T + 8)      // 12 staged input rows
#define XF (TROWS * 1024)    // 12288 floats = 48 KB -> 3 blocks/CU

// 4-byte-aligned float4: legal C++ for unaligned-by-16 global loads
typedef float f4u __attribute__((ext_vector_type(4), aligned(4)));

__launch_bounds__(256, 3)
__global__ void lc2d_kernel(const float* __restrict__ x,
                            const float* __restrict__ weight,
                            const float* __restrict__ bias,
                            float* __restrict__ out) {
    __shared__ float lds[XF];   // x tile: [row 0..11][wq 0..3][n 0..63][4]

    const int t    = threadIdx.x;
    const int lane = t & 63;          // batch index n (compute phase)
    const int wv   = t >> 6;          // wave 0..3

    const int h0 = blockIdx.y * H_T;
    const int w0 = blockIdx.x * W_T;

    // ---- stage x tile; thread t = (n = t>>2, wq = t&3) ----
    // global: 4 consecutive float4 per n (64B chunks, 16 lines/wave-instr)
    // LDS write addr = row*1024 + wq*256 + n*4 (4-way write conflict, one-time)
    {
        const int n  = t >> 2;
        const int wq = t & 3;
        const float* gx = x + (size_t)n * (H_IN * W_IN)
                            + (size_t)h0 * W_IN + w0 + wq * 4;
        float* ld = &lds[wq * 256 + n * 4];
        #pragma unroll
        for (int row = 0; row < TROWS; ++row) {
            const float4 v = *reinterpret_cast<const float4*>(gx + row * W_IN);
            *reinterpret_cast<float4*>(ld + row * 1024) = v;
        }
    }
    __syncthreads();

    const int wvu = __builtin_amdgcn_readfirstlane(wv);
    const int h   = h0 + wvu;                      // this wave's output row

    float acc[W_T];
    {
        const float* bptr = bias + (size_t)h * W_OUT + w0;   // uniform: s_load, pre-loop
        #pragma unroll
        for (int k = 0; k < W_T; ++k) acc[k] = bptr[k];
    }

    // wave-uniform weight base, forced onto the VMEM path; advances 9 floats/iter
    int vzero;
    asm volatile("v_mov_b32 %0, 0" : "=v"(vzero));
    const float* wp = weight + ((size_t)h * W_OUT + w0) * 81 + vzero;

    // x row base in LDS; advances 1024 floats/iter
    const float* xl = &lds[wv * 1024 + lane * 4];

    #pragma unroll 1
    for (int r = 0; r < 9; ++r) {
        // x row (wv + r): 16 floats/lane via 4 conflict-free ds_read_b128
        float xr[16];
        #pragma unroll
        for (int c = 0; c < 4; ++c) {
            const float4 v = *reinterpret_cast<const float4*>(xl + c * 256);
            xr[4 * c + 0] = v.x; xr[4 * c + 1] = v.y;
            xr[4 * c + 2] = v.z; xr[4 * c + 3] = v.w;
        }

        #pragma unroll
        for (int k = 0; k < W_T; ++k) {
            const float* wk = wp + k * 81;         // imm offsets: k*324 B (+32) < 4 KB
            const f4u a = *reinterpret_cast<const f4u*>(wk);      // taps 0..3
            const f4u b = *reinterpret_cast<const f4u*>(wk + 4);  // taps 4..7
            const float c8 = wk[8];                                // tap 8
            acc[k] = fmaf(a.x, xr[k + 0], acc[k]);
            acc[k] = fmaf(a.y, xr[k + 1], acc[k]);
            acc[k] = fmaf(a.z, xr[k + 2], acc[k]);
            acc[k] = fmaf(a.w, xr[k + 3], acc[k]);
            acc[k] = fmaf(b.x, xr[k + 4], acc[k]);
            acc[k] = fmaf(b.y, xr[k + 5], acc[k]);
            acc[k] = fmaf(b.z, xr[k + 6], acc[k]);
            acc[k] = fmaf(b.w, xr[k + 7], acc[k]);
            acc[k] = fmaf(c8,  xr[k + 8], acc[k]);
        }

        wp += 9;        // next tap-row
        xl += 1024;     // next x row
    }

    // ---- epilogue: ReLU + store (1 row x 8 floats per lane, 16B-aligned) ----
    float* o = out + (size_t)lane * (H_OUT * W_OUT) + (size_t)h * W_OUT + w0;
    float4 s;
    s.x = fmaxf(acc[0], 0.f); s.y = fmaxf(acc[1], 0.f);
    s.z = fmaxf(acc[2], 0.f); s.w = fmaxf(acc[3], 0.f);
    *reinterpret_cast<float4*>(o) = s;
    s.x = fmaxf(acc[4], 0.f); s.y = fmaxf(acc[5], 0.f);
    s.z = fmaxf(acc[6], 0.f); s.w = fmaxf(acc[7], 0.f);
    *reinterpret_cast<float4*>(o + 4) = s;
}

extern "C" void kernel_launch(void* const* d_in, const int* in_sizes, int n_in,
                              void* d_out, int out_size, void* d_ws, size_t ws_size,
                              hipStream_t stream) {
    const float* x      = (const float*)d_in[0];
    const float* weight = (const float*)d_in[1];
    const float* bias   = (const float*)d_in[2];
    float* out          = (float*)d_out;

    dim3 grid(W_OUT / W_T, H_OUT / H_T);   // 63 x 126
    dim3 block(256);
    lc2d_kernel<<<grid, block, 0, stream>>>(x, weight, bias, out);
}